// Round 1
// baseline (1298.915 us; speedup 1.0000x reference)
//
#include <hip/hip_runtime.h>
#include <cstdint>
#include <cstddef>

typedef __attribute__((ext_vector_type(8))) short bf16x8;   // 8 bf16 in 4 VGPRs
typedef __attribute__((ext_vector_type(4))) float f32x4;

__device__ __forceinline__ unsigned short f2bf(float f) {
  union { float f; unsigned u; } v; v.f = f;
  unsigned r = v.u + 0x7FFFu + ((v.u >> 16) & 1u);   // round-to-nearest-even
  return (unsigned short)(r >> 16);
}

// ---------------- elementwise fp32 -> bf16 ----------------
__global__ void cvt_x_kernel(const float* __restrict__ x, unsigned short* __restrict__ xb, int n4) {
  int i = blockIdx.x * blockDim.x + threadIdx.x;
  if (i >= n4) return;
  const float4 v = reinterpret_cast<const float4*>(x)[i];
  ushort4 o;
  o.x = f2bf(v.x); o.y = f2bf(v.y); o.z = f2bf(v.z); o.w = f2bf(v.w);
  reinterpret_cast<ushort4*>(xb)[i] = o;
}

// ---------------- transpose fp32 (K x N) -> bf16 (N x K) ----------------
__global__ void transpose_kernel(const float* __restrict__ src, unsigned short* __restrict__ dst,
                                 int K, int N) {
  __shared__ float t[32][33];
  const int tx = threadIdx.x, ty = threadIdx.y;
  const int n0 = blockIdx.x * 32, k0 = blockIdx.y * 32;
#pragma unroll
  for (int i = 0; i < 4; ++i)
    t[ty + i * 8][tx] = src[(size_t)(k0 + ty + i * 8) * N + n0 + tx];
  __syncthreads();
#pragma unroll
  for (int i = 0; i < 4; ++i)
    dst[(size_t)(n0 + ty + i * 8) * K + k0 + tx] = f2bf(t[tx][ty + i * 8]);
}

// ---------------- bf16 MFMA GEMM, 128x128 tile, BK=32 ----------------
// A: M x K (row-major bf16), B: N x K (row-major bf16, i.e. weights transposed)
// EPI==0: write fp32 C to yout[M][N]
// EPI==1: qkv epilogue: region = nblk/16 (0=q,1=k,2=v), h = nblk%16, RoPE on q/k.
#define GLL(gp, lp) __builtin_amdgcn_global_load_lds( \
    (const __attribute__((address_space(1))) void*)(gp), \
    (__attribute__((address_space(3))) void*)(lp), 16, 0, 0)

template <int EPI>
__global__ void gemm_bf16_kernel(
    const unsigned short* __restrict__ A, const unsigned short* __restrict__ B,
    int M, int N, int K,
    float* __restrict__ yout,
    const float* __restrict__ fcos, const float* __restrict__ fsin,
    unsigned short* __restrict__ q_ws, unsigned short* __restrict__ k_ws,
    unsigned short* __restrict__ vT_ws,
    float* __restrict__ k_out, float* __restrict__ v_out) {
  __shared__ unsigned short lsa[128 * 32];
  __shared__ unsigned short lsb[128 * 32];
  const int tid = threadIdx.x;
  const int w = tid >> 6, lane = tid & 63;
  const int wr = w >> 1, wc = w & 1;              // 2x2 wave grid, 64x64 per wave
  const int m0 = blockIdx.x * 128, n0 = blockIdx.y * 128;

  f32x4 acc[4][4] = {};

  const int stageRow = w * 32 + (lane >> 2);      // 16 rows per issue, 2 issues/wave/tile
  const int stageCol = (lane & 3) * 8;
  const unsigned short* aBase = A + (size_t)(m0 + stageRow) * K + stageCol;
  const unsigned short* bBase = B + (size_t)(n0 + stageRow) * K + stageCol;
  unsigned short* la = &lsa[(w * 32) * 32];
  unsigned short* lb = &lsb[(w * 32) * 32];

  const int kIters = K >> 5;
  for (int kk = 0; kk < kIters; ++kk) {
    const int k0 = kk << 5;
    __syncthreads();                               // protect LDS from prev-iter readers
    GLL(aBase + k0, la);
    GLL(aBase + (size_t)16 * K + k0, la + 16 * 32);
    GLL(bBase + k0, lb);
    GLL(bBase + (size_t)16 * K + k0, lb + 16 * 32);
    __syncthreads();                               // drains vmcnt before barrier
    bf16x8 af[4], bfr[4];
#pragma unroll
    for (int i = 0; i < 4; ++i)
      af[i] = *(const bf16x8*)&lsa[(wr * 64 + i * 16 + (lane & 15)) * 32 + (lane >> 4) * 8];
#pragma unroll
    for (int j = 0; j < 4; ++j)
      bfr[j] = *(const bf16x8*)&lsb[(wc * 64 + j * 16 + (lane & 15)) * 32 + (lane >> 4) * 8];
#pragma unroll
    for (int i = 0; i < 4; ++i)
#pragma unroll
      for (int j = 0; j < 4; ++j)
        acc[i][j] = __builtin_amdgcn_mfma_f32_16x16x32_bf16(af[i], bfr[j], acc[i][j], 0, 0, 0);
  }

  // ---- epilogue ----  C/D layout: col = lane&15, row = (lane>>4)*4 + r
  const int bn = blockIdx.y;
#pragma unroll
  for (int i = 0; i < 4; ++i) {
#pragma unroll
    for (int j = 0; j < 4; ++j) {
#pragma unroll
      for (int r = 0; r < 4; ++r) {
        const int m = m0 + wr * 64 + i * 16 + (lane >> 4) * 4 + r;
        const int n = n0 + wc * 64 + j * 16 + (lane & 15);
        const float val = acc[i][j][r];
        if (EPI == 0) {
          yout[(size_t)m * N + n] = val;
        } else {
          const int region = bn >> 4;   // tile of 128 cols == exactly one head
          const int h = bn & 15;
          const int b = m >> 11, t = m & 2047;
          const int dcol = n & 127;
          const size_t idx = ((size_t)((b * 16 + h) * 2048 + t)) * 128 + dcol;
          if (region == 2) {
            v_out[idx] = val;
            vT_ws[((size_t)(b * 16 + h) * 128 + dcol) * 2048 + t] = f2bf(val);
          } else {
            // RoPE: pair (2i, 2i+1) along n lives in lanes l, l^1 (same row)
            const int fi = dcol >> 1;
            const float c = fcos[t * 64 + fi];
            const float s = fsin[t * 64 + fi];
            const float part = __shfl_xor(val, 1);
            const float ro = (dcol & 1) ? (part * s + val * c) : (val * c - part * s);
            if (region == 0) {
              q_ws[idx] = f2bf(ro);
            } else {
              k_out[idx] = ro;
              k_ws[idx] = f2bf(ro);
            }
          }
        }
      }
    }
  }
}

// ---------------- flash attention ----------------
// block = 4 waves; wave w owns q rows [qt*64 + w*16, +16) of head bh. 32 keys/iter.
__global__ void attn_kernel(const unsigned short* __restrict__ q_ws,
                            const unsigned short* __restrict__ k_ws,
                            const unsigned short* __restrict__ vT_ws,
                            unsigned short* __restrict__ attnout) {
  __shared__ unsigned short plds[4][16][32];     // wave-private P tiles
  const int w = threadIdx.x >> 6, lane = threadIdx.x & 63;
  const int qt = blockIdx.x, bh = blockIdx.y;
  const int b = bh >> 4, h = bh & 15;
  const int qb = qt * 64 + w * 16;
  const size_t kvbase = (size_t)bh * 2048 * 128;

  bf16x8 qf[4];
#pragma unroll
  for (int c = 0; c < 4; ++c)
    qf[c] = *(const bf16x8*)&q_ws[kvbase + (size_t)(qb + (lane & 15)) * 128 + c * 32 + (lane >> 4) * 8];

  f32x4 acc[8] = {};
  float mrun[4], lrun[4];
#pragma unroll
  for (int r = 0; r < 4; ++r) { mrun[r] = -1e30f; lrun[r] = 0.0f; }

  const float scale = 0.08838834764831845f;      // 1/sqrt(128)
  const int kmax = qb + 16;
  for (int kt = 0; kt < kmax; kt += 32) {
    f32x4 s0 = {0.f, 0.f, 0.f, 0.f}, s1 = {0.f, 0.f, 0.f, 0.f};
#pragma unroll
    for (int c = 0; c < 4; ++c) {
      bf16x8 kf0 = *(const bf16x8*)&k_ws[kvbase + (size_t)(kt + (lane & 15)) * 128 + c * 32 + (lane >> 4) * 8];
      bf16x8 kf1 = *(const bf16x8*)&k_ws[kvbase + (size_t)(kt + 16 + (lane & 15)) * 128 + c * 32 + (lane >> 4) * 8];
      s0 = __builtin_amdgcn_mfma_f32_16x16x32_bf16(qf[c], kf0, s0, 0, 0, 0);
      s1 = __builtin_amdgcn_mfma_f32_16x16x32_bf16(qf[c], kf1, s1, 0, 0, 0);
    }
    const bool boundary = (kt + 32 > qb);        // wave-uniform
#pragma unroll
    for (int r = 0; r < 4; ++r) {
      float v0 = s0[r] * scale;
      float v1 = s1[r] * scale;
      if (boundary) {
        const int row = qb + (lane >> 4) * 4 + r;
        const int key0 = kt + (lane & 15);
        if (key0 > row) v0 = -1e30f;
        if (key0 + 16 > row) v1 = -1e30f;
      }
      float tm = fmaxf(v0, v1);
      tm = fmaxf(tm, __shfl_xor(tm, 1));
      tm = fmaxf(tm, __shfl_xor(tm, 2));
      tm = fmaxf(tm, __shfl_xor(tm, 4));
      tm = fmaxf(tm, __shfl_xor(tm, 8));
      const float mnew = fmaxf(mrun[r], tm);
      const float sc = __expf(mrun[r] - mnew);
      const float p0 = __expf(v0 - mnew);
      const float p1 = __expf(v1 - mnew);
      float ps = p0 + p1;
      ps += __shfl_xor(ps, 1);
      ps += __shfl_xor(ps, 2);
      ps += __shfl_xor(ps, 4);
      ps += __shfl_xor(ps, 8);
      lrun[r] = lrun[r] * sc + ps;
      mrun[r] = mnew;
#pragma unroll
      for (int n = 0; n < 8; ++n) acc[n][r] *= sc;
      plds[w][(lane >> 4) * 4 + r][(lane & 15)] = f2bf(p0);
      plds[w][(lane >> 4) * 4 + r][16 + (lane & 15)] = f2bf(p1);
    }
    // wave-private LDS round-trip: drain DS writes, fence the scheduler (rule #18)
    asm volatile("s_waitcnt lgkmcnt(0)" ::: "memory");
    __builtin_amdgcn_sched_barrier(0);
    bf16x8 pa = *(const bf16x8*)&plds[w][lane & 15][(lane >> 4) * 8];
#pragma unroll
    for (int n = 0; n < 8; ++n) {
      bf16x8 vf = *(const bf16x8*)&vT_ws[kvbase + (size_t)(n * 16 + (lane & 15)) * 2048 + kt + (lane >> 4) * 8];
      acc[n] = __builtin_amdgcn_mfma_f32_16x16x32_bf16(pa, vf, acc[n], 0, 0, 0);
    }
  }
#pragma unroll
  for (int n = 0; n < 8; ++n)
#pragma unroll
    for (int r = 0; r < 4; ++r) {
      const int q = qb + (lane >> 4) * 4 + r;
      const int d = n * 16 + (lane & 15);
      attnout[((size_t)(b * 2048 + q)) * 2048 + h * 128 + d] = f2bf(acc[n][r] / lrun[r]);
    }
}

extern "C" void kernel_launch(void* const* d_in, const int* in_sizes, int n_in,
                              void* d_out, int out_size, void* d_ws, size_t ws_size,
                              hipStream_t stream) {
  (void)in_sizes; (void)n_in; (void)out_size; (void)ws_size;
  const float* x    = (const float*)d_in[0];
  const float* fcos = (const float*)d_in[1];
  const float* fsin = (const float*)d_in[2];
  const float* Wqkv = (const float*)d_in[3];
  const float* Wout = (const float*)d_in[4];

  float* out   = (float*)d_out;
  float* y_out = out;
  float* k_out = out + (size_t)16777216;          // B*T*C
  float* v_out = out + (size_t)33554432;

  // workspace layout (bf16 elements), total 167.8 MB
  unsigned short* xb      = (unsigned short*)d_ws;     // 8192 x 2048
  unsigned short* wqkvT   = xb + 16777216;             // 6144 x 2048
  unsigned short* woutT   = wqkvT + 12582912;          // 2048 x 2048
  unsigned short* q_ws    = woutT + 4194304;           // (B,H,T,hd)
  unsigned short* k_ws    = q_ws + 16777216;           // (B,H,T,hd)
  unsigned short* vT_ws   = k_ws + 16777216;           // (B,H,hd,T)
  unsigned short* attnout = xb;                        // alias: x consumed by then

  cvt_x_kernel<<<16384, 256, 0, stream>>>(x, xb, 4194304);
  transpose_kernel<<<dim3(192, 64), dim3(32, 8), 0, stream>>>(Wqkv, wqkvT, 2048, 6144);
  transpose_kernel<<<dim3(64, 64), dim3(32, 8), 0, stream>>>(Wout, woutT, 2048, 2048);

  gemm_bf16_kernel<1><<<dim3(64, 48), 256, 0, stream>>>(
      xb, wqkvT, 8192, 6144, 2048,
      nullptr, fcos, fsin, q_ws, k_ws, vT_ws, k_out, v_out);

  attn_kernel<<<dim3(32, 64), 256, 0, stream>>>(q_ws, k_ws, vT_ws, attnout);

  gemm_bf16_kernel<0><<<dim3(64, 16), 256, 0, stream>>>(
      attnout, woutT, 8192, 2048, 2048,
      y_out, nullptr, nullptr, nullptr, nullptr, nullptr, nullptr, nullptr);
}

// Round 2
// 533.648 us; speedup vs baseline: 2.4340x; 2.4340x over previous
//
#include <hip/hip_runtime.h>
#include <cstdint>
#include <cstddef>

typedef __attribute__((ext_vector_type(8))) short bf16x8;   // 8 bf16 in 4 VGPRs
typedef __attribute__((ext_vector_type(4))) float f32x4;

__device__ __forceinline__ unsigned short f2bf(float f) {
  union { float f; unsigned u; } v; v.f = f;
  unsigned r = v.u + 0x7FFFu + ((v.u >> 16) & 1u);   // round-to-nearest-even
  return (unsigned short)(r >> 16);
}

#define GLL(gp, lp) __builtin_amdgcn_global_load_lds( \
    (const __attribute__((address_space(1))) void*)(gp), \
    (__attribute__((address_space(3))) void*)(lp), 16, 0, 0)

// ---------------- elementwise fp32 -> bf16 ----------------
__global__ void cvt_x_kernel(const float* __restrict__ x, unsigned short* __restrict__ xb, int n4) {
  int i = blockIdx.x * blockDim.x + threadIdx.x;
  if (i >= n4) return;
  const float4 v = reinterpret_cast<const float4*>(x)[i];
  ushort4 o;
  o.x = f2bf(v.x); o.y = f2bf(v.y); o.z = f2bf(v.z); o.w = f2bf(v.w);
  reinterpret_cast<ushort4*>(xb)[i] = o;
}

// ---------------- transpose fp32 (K x N) -> bf16 (N x K) ----------------
__global__ void transpose_kernel(const float* __restrict__ src, unsigned short* __restrict__ dst,
                                 int K, int N) {
  __shared__ float t[32][33];
  const int tx = threadIdx.x, ty = threadIdx.y;
  const int n0 = blockIdx.x * 32, k0 = blockIdx.y * 32;
#pragma unroll
  for (int i = 0; i < 4; ++i)
    t[ty + i * 8][tx] = src[(size_t)(k0 + ty + i * 8) * N + n0 + tx];
  __syncthreads();
#pragma unroll
  for (int i = 0; i < 4; ++i)
    dst[(size_t)(n0 + ty + i * 8) * K + k0 + tx] = f2bf(t[tx][ty + i * 8]);
}

// ---------------- bf16 MFMA GEMM, 128x128 tile, BK=32 ----------------
template <int EPI>
__global__ void gemm_bf16_kernel(
    const unsigned short* __restrict__ A, const unsigned short* __restrict__ B,
    int M, int N, int K,
    float* __restrict__ yout,
    const float* __restrict__ fcos, const float* __restrict__ fsin,
    unsigned short* __restrict__ q_ws, unsigned short* __restrict__ k_ws,
    unsigned short* __restrict__ vT_ws,
    float* __restrict__ k_out, float* __restrict__ v_out) {
  __shared__ unsigned short lsa[128 * 32];
  __shared__ unsigned short lsb[128 * 32];
  const int tid = threadIdx.x;
  const int w = tid >> 6, lane = tid & 63;
  const int wr = w >> 1, wc = w & 1;              // 2x2 wave grid, 64x64 per wave
  const int m0 = blockIdx.x * 128, n0 = blockIdx.y * 128;

  f32x4 acc[4][4] = {};

  const int stageRow = w * 32 + (lane >> 2);
  const int stageCol = (lane & 3) * 8;
  const unsigned short* aBase = A + (size_t)(m0 + stageRow) * K + stageCol;
  const unsigned short* bBase = B + (size_t)(n0 + stageRow) * K + stageCol;
  unsigned short* la = &lsa[(w * 32) * 32];
  unsigned short* lb = &lsb[(w * 32) * 32];

  const int kIters = K >> 5;
  for (int kk = 0; kk < kIters; ++kk) {
    const int k0 = kk << 5;
    __syncthreads();
    GLL(aBase + k0, la);
    GLL(aBase + (size_t)16 * K + k0, la + 16 * 32);
    GLL(bBase + k0, lb);
    GLL(bBase + (size_t)16 * K + k0, lb + 16 * 32);
    __syncthreads();
    bf16x8 af[4], bfr[4];
#pragma unroll
    for (int i = 0; i < 4; ++i)
      af[i] = *(const bf16x8*)&lsa[(wr * 64 + i * 16 + (lane & 15)) * 32 + (lane >> 4) * 8];
#pragma unroll
    for (int j = 0; j < 4; ++j)
      bfr[j] = *(const bf16x8*)&lsb[(wc * 64 + j * 16 + (lane & 15)) * 32 + (lane >> 4) * 8];
#pragma unroll
    for (int i = 0; i < 4; ++i)
#pragma unroll
      for (int j = 0; j < 4; ++j)
        acc[i][j] = __builtin_amdgcn_mfma_f32_16x16x32_bf16(af[i], bfr[j], acc[i][j], 0, 0, 0);
  }

  const int bn = blockIdx.y;
#pragma unroll
  for (int i = 0; i < 4; ++i) {
#pragma unroll
    for (int j = 0; j < 4; ++j) {
#pragma unroll
      for (int r = 0; r < 4; ++r) {
        const int m = m0 + wr * 64 + i * 16 + (lane >> 4) * 4 + r;
        const int n = n0 + wc * 64 + j * 16 + (lane & 15);
        const float val = acc[i][j][r];
        if (EPI == 0) {
          yout[(size_t)m * N + n] = val;
        } else {
          const int region = bn >> 4;
          const int h = bn & 15;
          const int b = m >> 11, t = m & 2047;
          const int dcol = n & 127;
          const size_t idx = ((size_t)((b * 16 + h) * 2048 + t)) * 128 + dcol;
          if (region == 2) {
            v_out[idx] = val;
            vT_ws[((size_t)(b * 16 + h) * 128 + dcol) * 2048 + t] = f2bf(val);
          } else {
            const int fi = dcol >> 1;
            const float c = fcos[t * 64 + fi];
            const float s = fsin[t * 64 + fi];
            const float part = __shfl_xor(val, 1);
            const float ro = (dcol & 1) ? (part * s + val * c) : (val * c - part * s);
            if (region == 0) {
              q_ws[idx] = f2bf(ro * 0.08838834764831845f);   // fold 1/sqrt(hd) into Q
            } else {
              k_out[idx] = ro;
              k_ws[idx] = f2bf(ro);
            }
          }
        }
      }
    }
  }
}

// ---------------- flash attention v2 ----------------
// Block = 4 waves, 128 q-rows (32/wave, 2 subtiles of 16). KV staged 64 keys/iter
// in LDS (double-buffered, XOR-swizzled via pre-swizzled global source).
// Swapped QK^T: S^T layout -> lane-local-ish softmax (2 shuffles per 64 keys).
__global__ __launch_bounds__(256, 2) void attn_kernel(
    const unsigned short* __restrict__ q_ws,
    const unsigned short* __restrict__ k_ws,
    const unsigned short* __restrict__ vT_ws,
    unsigned short* __restrict__ attnout) {
  __shared__ unsigned short Kl[2][64 * 128];    // [key][d], chunk16 ^= (key&7)
  __shared__ unsigned short Vl[2][128 * 64];    // [d][key], chunk16 ^= (d&7)
  __shared__ unsigned short Pl[4][2][16 * 64];  // per-wave per-qsub, byte ^= (q&7)<<4

  const int tid = threadIdx.x;
  const int w = tid >> 6, lane = tid & 63;
  const int g = lane >> 4, q16 = lane & 15;
  const int bh = blockIdx.x;
  const int qt = 15 - (int)blockIdx.y;          // heaviest q-tiles dispatched first
  const int b = bh >> 4, h = bh & 15;
  const int qbase = qt * 128;
  const int qb = qbase + w * 32;
  const size_t kvbase = (size_t)bh * 2048 * 128;

  // staging lane decomposition
  const int krow_l = lane >> 4, kchunk = lane & 15;   // K: 4 rows x 16 chunks per instr
  const int vrow_l = lane >> 3, vchunk = lane & 7;    // V: 8 rows x 8 chunks per instr

  // Q fragments in registers (B-operand: rows q, d-contig), pre-scaled
  bf16x8 qf[2][4];
#pragma unroll
  for (int qs = 0; qs < 2; ++qs)
#pragma unroll
    for (int c = 0; c < 4; ++c)
      qf[qs][c] = *(const bf16x8*)&q_ws[kvbase + (size_t)(qb + qs * 16 + q16) * 128 + c * 32 + g * 8];

  f32x4 acc[2][8] = {};
  float mrun[2] = {-1e30f, -1e30f};
  float lrun[2] = {0.f, 0.f};

  const int nt = (qt + 1) * 2;

  auto stageK = [&](int buf, int kt) {
#pragma unroll
    for (int i = 0; i < 4; ++i) {
      const int slab = w * 4 + i;                     // 4 key-rows per slab
      const int krow = slab * 4 + krow_l;
      GLL(k_ws + kvbase + (size_t)(kt + krow) * 128 + ((kchunk ^ (krow & 7)) << 3),
          ((unsigned short*)Kl[buf]) + slab * 512);
    }
  };
  auto stageV = [&](int buf, int kt) {
#pragma unroll
    for (int i = 0; i < 4; ++i) {
      const int slab = w * 4 + i;                     // 8 d-rows per slab
      const int d = slab * 8 + vrow_l;
      GLL(vT_ws + kvbase + (size_t)d * 2048 + kt + ((vchunk ^ (d & 7)) << 3),
          ((unsigned short*)Vl[buf]) + slab * 512);
    }
  };

  stageK(0, 0); stageV(0, 0);
  int cur = 0;
  for (int it = 0; it < nt; ++it) {
    const int kt = it * 64;
    __syncthreads();                                   // staged tile `cur` ready
    if (it + 1 < nt) { stageK(cur ^ 1, kt + 64); stageV(cur ^ 1, kt + 64); }

    if (kt <= qb + 31) {                               // wave has live rows for this tile
      // ---- QK^T (swapped): s[qs][t][r] = S[key = kt+t*16+g*4+r][q = qb+qs*16+q16]
      f32x4 s[2][4];
#pragma unroll
      for (int qs = 0; qs < 2; ++qs)
#pragma unroll
        for (int t = 0; t < 4; ++t) s[qs][t] = f32x4{0.f, 0.f, 0.f, 0.f};
#pragma unroll
      for (int t = 0; t < 4; ++t) {
        const int key = t * 16 + q16;
#pragma unroll
        for (int c = 0; c < 4; ++c) {
          bf16x8 kf = *(const bf16x8*)&Kl[cur][key * 128 + (((c * 4 + g) ^ (key & 7)) << 3)];
          s[0][t] = __builtin_amdgcn_mfma_f32_16x16x32_bf16(kf, qf[0][c], s[0][t], 0, 0, 0);
          s[1][t] = __builtin_amdgcn_mfma_f32_16x16x32_bf16(kf, qf[1][c], s[1][t], 0, 0, 0);
        }
      }

      // ---- softmax per q-subtile (q = lane&15 space) ----
#pragma unroll
      for (int qs = 0; qs < 2; ++qs) {
        const int qrow = qb + qs * 16 + q16;
        if (kt + 64 > qb + qs * 16) {                  // boundary: causal mask
#pragma unroll
          for (int t = 0; t < 4; ++t)
#pragma unroll
            for (int r = 0; r < 4; ++r)
              if (kt + t * 16 + g * 4 + r > qrow) s[qs][t][r] = -1e30f;
        }
        float tm = s[qs][0][0];
#pragma unroll
        for (int t = 0; t < 4; ++t)
#pragma unroll
          for (int r = 0; r < 4; ++r) tm = fmaxf(tm, s[qs][t][r]);
        tm = fmaxf(tm, __shfl_xor(tm, 16));
        tm = fmaxf(tm, __shfl_xor(tm, 32));
        if (__any(tm > mrun[qs] + 8.0f)) {             // T13 defer-max
          const float mnew = fmaxf(mrun[qs], tm);
          const float fac = __expf(mrun[qs] - mnew);
          lrun[qs] *= fac;
          mrun[qs] = mnew;
          float fr0 = __shfl(fac, g * 4 + 0), fr1 = __shfl(fac, g * 4 + 1);
          float fr2 = __shfl(fac, g * 4 + 2), fr3 = __shfl(fac, g * 4 + 3);
#pragma unroll
          for (int n = 0; n < 8; ++n) {
            acc[qs][n][0] *= fr0; acc[qs][n][1] *= fr1;
            acc[qs][n][2] *= fr2; acc[qs][n][3] *= fr3;
          }
        }
        float ps = 0.f;
        unsigned pk[8];
#pragma unroll
        for (int t = 0; t < 4; ++t) {
          const float p0 = __expf(s[qs][t][0] - mrun[qs]);
          const float p1 = __expf(s[qs][t][1] - mrun[qs]);
          const float p2 = __expf(s[qs][t][2] - mrun[qs]);
          const float p3 = __expf(s[qs][t][3] - mrun[qs]);
          ps += (p0 + p1) + (p2 + p3);
          pk[t * 2]     = (unsigned)f2bf(p0) | ((unsigned)f2bf(p1) << 16);
          pk[t * 2 + 1] = (unsigned)f2bf(p2) | ((unsigned)f2bf(p3) << 16);
        }
        ps += __shfl_xor(ps, 16);
        ps += __shfl_xor(ps, 32);
        lrun[qs] += ps;
#pragma unroll
        for (int t = 0; t < 4; ++t) {
          const unsigned byteoff = (unsigned)(q16 * 128) +
              (((unsigned)(t * 32 + g * 8)) ^ ((unsigned)(q16 & 7) << 4));
          *(uint2*)((char*)&Pl[w][qs][0] + byteoff) = make_uint2(pk[t * 2], pk[t * 2 + 1]);
        }
      }

      // ---- PV: O[q][d] += P[q][keys] * V^T[d][keys] ----
#pragma unroll
      for (int ks = 0; ks < 2; ++ks) {
        const unsigned pcol = ((unsigned)(ks * 64 + g * 16)) ^ ((unsigned)(q16 & 7) << 4);
        bf16x8 pa0 = *(const bf16x8*)((char*)&Pl[w][0][0] + q16 * 128 + pcol);
        bf16x8 pa1 = *(const bf16x8*)((char*)&Pl[w][1][0] + q16 * 128 + pcol);
#pragma unroll
        for (int n = 0; n < 8; ++n) {
          const int d = n * 16 + q16;
          bf16x8 vf = *(const bf16x8*)&Vl[cur][d * 64 + (((ks * 4 + g) ^ (d & 7)) << 3)];
          acc[0][n] = __builtin_amdgcn_mfma_f32_16x16x32_bf16(pa0, vf, acc[0][n], 0, 0, 0);
          acc[1][n] = __builtin_amdgcn_mfma_f32_16x16x32_bf16(pa1, vf, acc[1][n], 0, 0, 0);
        }
      }
    }
    cur ^= 1;
  }

  // ---- epilogue: normalize + store ----
#pragma unroll
  for (int qs = 0; qs < 2; ++qs) {
    float rl[4];
#pragma unroll
    for (int r = 0; r < 4; ++r) rl[r] = 1.0f / __shfl(lrun[qs], g * 4 + r);
#pragma unroll
    for (int n = 0; n < 8; ++n) {
#pragma unroll
      for (int r = 0; r < 4; ++r) {
        const int q = qb + qs * 16 + g * 4 + r;
        const int d = n * 16 + q16;
        attnout[((size_t)(b * 2048 + q)) * 2048 + h * 128 + d] = f2bf(acc[qs][n][r] * rl[r]);
      }
    }
  }
}

extern "C" void kernel_launch(void* const* d_in, const int* in_sizes, int n_in,
                              void* d_out, int out_size, void* d_ws, size_t ws_size,
                              hipStream_t stream) {
  (void)in_sizes; (void)n_in; (void)out_size; (void)ws_size;
  const float* x    = (const float*)d_in[0];
  const float* fcos = (const float*)d_in[1];
  const float* fsin = (const float*)d_in[2];
  const float* Wqkv = (const float*)d_in[3];
  const float* Wout = (const float*)d_in[4];

  float* out   = (float*)d_out;
  float* y_out = out;
  float* k_out = out + (size_t)16777216;          // B*T*C
  float* v_out = out + (size_t)33554432;

  unsigned short* xb      = (unsigned short*)d_ws;     // 8192 x 2048
  unsigned short* wqkvT   = xb + 16777216;             // 6144 x 2048
  unsigned short* woutT   = wqkvT + 12582912;          // 2048 x 2048
  unsigned short* q_ws    = woutT + 4194304;           // (B,H,T,hd) pre-scaled
  unsigned short* k_ws    = q_ws + 16777216;           // (B,H,T,hd)
  unsigned short* vT_ws   = k_ws + 16777216;           // (B,H,hd,T)
  unsigned short* attnout = xb;                        // alias: x consumed by then

  cvt_x_kernel<<<16384, 256, 0, stream>>>(x, xb, 4194304);
  transpose_kernel<<<dim3(192, 64), dim3(32, 8), 0, stream>>>(Wqkv, wqkvT, 2048, 6144);
  transpose_kernel<<<dim3(64, 64), dim3(32, 8), 0, stream>>>(Wout, woutT, 2048, 2048);

  gemm_bf16_kernel<1><<<dim3(64, 48), 256, 0, stream>>>(
      xb, wqkvT, 8192, 6144, 2048,
      nullptr, fcos, fsin, q_ws, k_ws, vT_ws, k_out, v_out);

  attn_kernel<<<dim3(64, 16), 256, 0, stream>>>(q_ws, k_ws, vT_ws, attnout);

  gemm_bf16_kernel<0><<<dim3(64, 16), 256, 0, stream>>>(
      attnout, woutT, 8192, 2048, 2048,
      y_out, nullptr, nullptr, nullptr, nullptr, nullptr, nullptr, nullptr);
}